// Round 6
// baseline (2435.089 us; speedup 1.0000x reference)
//
#include <hip/hip_runtime.h>
#include <math.h>
#include <stdint.h>

#define GIN_DIM 512
#define GHID_DIM 512
#define GOUT_DIM 64
#define GHOP 10
#define NSLICE 8

typedef __attribute__((ext_vector_type(8))) short short8;
typedef __attribute__((ext_vector_type(4))) float f32x4;

__device__ __forceinline__ unsigned f2bf_bits(float f) {
  unsigned u = __float_as_uint(f);
  return (u + 0x7FFFu + ((u >> 16) & 1u)) >> 16;
}
__device__ __forceinline__ float bf2f_bits(unsigned h) { return __uint_as_float(h << 16); }
__device__ __forceinline__ int slot_sw(int r, int o) { return (o ^ r) & 7; }

// ---------------- CSR build (XCD-sliced: slice s -> XCD s via blockIdx%8) ----------------

__global__ __launch_bounds__(256) void k_count(const int* __restrict__ row, int* __restrict__ cnt,
                                               int E, float sliceScale) {
  int slice = blockIdx.x & (NSLICE - 1);
  int base = ((blockIdx.x >> 3) * 256 + threadIdx.x) * 4;
  if (base + 3 < E) {
    int4 r4 = *(const int4*)(row + base);
    int rr[4] = {r4.x, r4.y, r4.z, r4.w};
#pragma unroll
    for (int j = 0; j < 4; ++j) {
      int sl = min(NSLICE - 1, (int)((float)rr[j] * sliceScale));
      if (sl == slice) atomicAdd(&cnt[rr[j]], 1);
    }
  } else {
    for (int j = 0; j < 4; ++j) {
      int e = base + j;
      if (e < E) {
        int r = row[e];
        int sl = min(NSLICE - 1, (int)((float)r * sliceScale));
        if (sl == slice) atomicAdd(&cnt[r], 1);
      }
    }
  }
}

// pass1: per-block (1024 elems) reduce
__global__ __launch_bounds__(256) void k_scan1(const int* __restrict__ cnt,
                                               int* __restrict__ bsum, int n) {
  __shared__ int sd[256];
  int b = blockIdx.x, t = threadIdx.x;
  int base = b * 1024 + t * 4;
  int s = 0;
#pragma unroll
  for (int j = 0; j < 4; ++j) {
    int i = base + j;
    if (i < n) s += cnt[i];
  }
  sd[t] = s;
  __syncthreads();
  for (int off = 128; off; off >>= 1) {
    if (t < off) sd[t] += sd[t + off];
    __syncthreads();
  }
  if (t == 0) bsum[b] = sd[0];
}

// pass2: exclusive scan of block sums (nb <= 128), writes rp[n]=total
__global__ __launch_bounds__(128) void k_scan2(int* __restrict__ bsum, int* __restrict__ rp,
                                               int nb, int n) {
  __shared__ int sd[128];
  int t = threadIdx.x;
  int v = (t < nb) ? bsum[t] : 0;
  int incl = v;
  sd[t] = incl;
  __syncthreads();
  for (int off = 1; off < 128; off <<= 1) {
    int add = (t >= off) ? sd[t - off] : 0;
    __syncthreads();
    incl += add;
    sd[t] = incl;
    __syncthreads();
  }
  if (t < nb) bsum[t] = incl - v;  // exclusive
  if (t == nb - 1) rp[n] = incl;   // total
}

// pass3: block-local scan + apply, write rp and nxt
__global__ __launch_bounds__(256) void k_scan3(const int* __restrict__ cnt,
                                               const int* __restrict__ bsum,
                                               int* __restrict__ rp, int* __restrict__ nxt,
                                               int n) {
  __shared__ int sd[256];
  int b = blockIdx.x, t = threadIdx.x;
  int base = b * 1024 + t * 4;
  int v[4];
  int s = 0;
#pragma unroll
  for (int j = 0; j < 4; ++j) {
    int i = base + j;
    v[j] = (i < n) ? cnt[i] : 0;
    s += v[j];
  }
  int incl = s;
  sd[t] = incl;
  __syncthreads();
  for (int off = 1; off < 256; off <<= 1) {
    int add = (t >= off) ? sd[t - off] : 0;
    __syncthreads();
    incl += add;
    sd[t] = incl;
    __syncthreads();
  }
  int run = incl - s + bsum[b];
#pragma unroll
  for (int j = 0; j < 4; ++j) {
    int i = base + j;
    if (i < n) {
      rp[i] = run;
      nxt[i] = run;
      run += v[j];
    }
  }
}

__global__ __launch_bounds__(256) void k_scatter(const int* __restrict__ row,
                                                 const int* __restrict__ col,
                                                 const float* __restrict__ ew,
                                                 int* __restrict__ nxt, int2* __restrict__ epk,
                                                 int E, float sliceScale) {
  int slice = blockIdx.x & (NSLICE - 1);
  int base = ((blockIdx.x >> 3) * 256 + threadIdx.x) * 4;
  if (base + 3 < E) {
    int4 r4 = *(const int4*)(row + base);
    int rr[4] = {r4.x, r4.y, r4.z, r4.w};
#pragma unroll
    for (int j = 0; j < 4; ++j) {
      int sl = min(NSLICE - 1, (int)((float)rr[j] * sliceScale));
      if (sl == slice) {
        int e = base + j;
        int p = atomicAdd(&nxt[rr[j]], 1);
        epk[p] = make_int2(col[e], __float_as_int(ew[e]));
      }
    }
  } else {
    for (int j = 0; j < 4; ++j) {
      int e = base + j;
      if (e < E) {
        int r = row[e];
        int sl = min(NSLICE - 1, (int)((float)r * sliceScale));
        if (sl == slice) {
          int p = atomicAdd(&nxt[r], 1);
          epk[p] = make_int2(col[e], __float_as_int(ew[e]));
        }
      }
    }
  }
}

// ---------------- W1 transpose + bf16 hi/lo split: W1[512k][512n] -> W1t[n][k] ----------------

__global__ __launch_bounds__(1024) void k_w1t(const float* __restrict__ w1,
                                              ushort* __restrict__ hi,
                                              ushort* __restrict__ lo) {
  __shared__ float t[32][33];
  int bx = blockIdx.x;  // n tile
  int by = blockIdx.y;  // k tile
  int tx = threadIdx.x & 31, ty = threadIdx.x >> 5;
  t[ty][tx] = w1[(size_t)(by * 32 + ty) * GHID_DIM + bx * 32 + tx];
  __syncthreads();
  float v = t[tx][ty];  // = w1[by*32+tx][bx*32+ty]
  unsigned h = f2bf_bits(v);
  unsigned l = f2bf_bits(v - bf2f_bits(h));
  size_t o = (size_t)(bx * 32 + ty) * GIN_DIM + by * 32 + tx;
  hi[o] = (ushort)h;
  lo[o] = (ushort)l;
}

// ---------------- fused dense front: plane = relu(x@W1+b1)@W2 + b2 ----------------
// BM=128 rows/block, 4 hid-chunks of 128 looped inside; GEMM2 accumulated in regs.

__global__ __launch_bounds__(256, 2) void k_dense(
    const float* __restrict__ x, const ushort* __restrict__ w1h, const ushort* __restrict__ w1l,
    const float* __restrict__ b1, const float* __restrict__ w2, const float* __restrict__ b2,
    float* __restrict__ plane, int n) {
  __shared__ __align__(16) ushort Ah[128 * 64];
  __shared__ __align__(16) ushort Al[128 * 64];
  __shared__ __align__(16) ushort Bh[128 * 64];
  __shared__ __align__(16) ushort Bl[128 * 64];
  int tid = threadIdx.x;
  int wave = tid >> 6, lane = tid & 63;
  int wm = wave >> 1, wn = wave & 1;
  int fr = lane & 15, fq = lane >> 4;
  int rowbase = blockIdx.x * 128;
  int sr = tid >> 1;        // staged row / col 0..127
  int sk = (tid & 1) * 32;  // k offset within BK tile

  f32x4 acc2[2][4];
#pragma unroll
  for (int m2 = 0; m2 < 2; ++m2)
#pragma unroll
    for (int q2 = 0; q2 < 4; ++q2) {
      float bv = b2[q2 * 16 + fr];
      acc2[m2][q2] = (f32x4)(bv);
    }

  for (int c = 0; c < 4; ++c) {
    int cbase = c * 128;
    f32x4 acc[4][4];
#pragma unroll
    for (int m = 0; m < 4; ++m)
#pragma unroll
      for (int q = 0; q < 4; ++q) acc[m][q] = (f32x4)(0.f);

    // ---- GEMM1: acc = x @ W1[:, cbase:cbase+128] ----
    for (int ks = 0; ks < GIN_DIM; ks += 64) {
      {  // stage A from x (fp32 -> hi/lo bf16), swizzled octets
        int gr = rowbase + sr;
        float vals[32];
        if (gr < n) {
          const float* px = x + (size_t)gr * GIN_DIM + ks + sk;
#pragma unroll
          for (int q = 0; q < 8; ++q) {
            float4 v = *(const float4*)(px + q * 4);
            vals[q * 4 + 0] = v.x;
            vals[q * 4 + 1] = v.y;
            vals[q * 4 + 2] = v.z;
            vals[q * 4 + 3] = v.w;
          }
        } else {
#pragma unroll
          for (int q = 0; q < 32; ++q) vals[q] = 0.f;
        }
#pragma unroll
        for (int o4 = 0; o4 < 4; ++o4) {
          short8 vh, vl;
#pragma unroll
          for (int j = 0; j < 8; ++j) {
            float a = vals[o4 * 8 + j];
            unsigned hb = f2bf_bits(a);
            float r = a - bf2f_bits(hb);
            unsigned lb = f2bf_bits(r);
            vh[j] = (short)hb;
            vl[j] = (short)lb;
          }
          int oct = (sk >> 3) + o4;
          int off = sr * 64 + slot_sw(sr, oct) * 8;
          *reinterpret_cast<short8*>(&Ah[off]) = vh;
          *reinterpret_cast<short8*>(&Al[off]) = vl;
        }
      }
      {  // stage B from pre-split W1t rows
        const ushort* ph = w1h + (size_t)(cbase + sr) * GIN_DIM + ks + sk;
        const ushort* pl = w1l + (size_t)(cbase + sr) * GIN_DIM + ks + sk;
#pragma unroll
        for (int o4 = 0; o4 < 4; ++o4) {
          short8 vh = *reinterpret_cast<const short8*>(ph + o4 * 8);
          short8 vl = *reinterpret_cast<const short8*>(pl + o4 * 8);
          int oct = (sk >> 3) + o4;
          int off = sr * 64 + slot_sw(sr, oct) * 8;
          *reinterpret_cast<short8*>(&Bh[off]) = vh;
          *reinterpret_cast<short8*>(&Bl[off]) = vl;
        }
      }
      __syncthreads();
#pragma unroll
      for (int kk = 0; kk < 2; ++kk) {
        int koct = kk * 4 + fq;
        short8 bH[4], bL[4];
#pragma unroll
        for (int q = 0; q < 4; ++q) {
          int cc = wn * 64 + q * 16 + fr;
          int off = cc * 64 + slot_sw(cc, koct) * 8;
          bH[q] = *reinterpret_cast<const short8*>(&Bh[off]);
          bL[q] = *reinterpret_cast<const short8*>(&Bl[off]);
        }
#pragma unroll
        for (int m = 0; m < 4; ++m) {
          int r = wm * 64 + m * 16 + fr;
          int off = r * 64 + slot_sw(r, koct) * 8;
          short8 aH = *reinterpret_cast<const short8*>(&Ah[off]);
          short8 aL = *reinterpret_cast<const short8*>(&Al[off]);
#pragma unroll
          for (int q = 0; q < 4; ++q) {
            f32x4 t = acc[m][q];
            t = __builtin_amdgcn_mfma_f32_16x16x32_bf16(aH, bL[q], t, 0, 0, 0);
            t = __builtin_amdgcn_mfma_f32_16x16x32_bf16(aL, bH[q], t, 0, 0, 0);
            t = __builtin_amdgcn_mfma_f32_16x16x32_bf16(aH, bH[q], t, 0, 0, 0);
            acc[m][q] = t;
          }
        }
      }
      __syncthreads();
    }

    // bias + relu in registers
#pragma unroll
    for (int m = 0; m < 4; ++m)
#pragma unroll
      for (int q = 0; q < 4; ++q) {
        float bias = b1[cbase + wn * 64 + q * 16 + fr];
#pragma unroll
        for (int j = 0; j < 4; ++j) acc[m][q][j] = fmaxf(acc[m][q][j] + bias, 0.f);
      }

    // ---- GEMM2: acc2 += h_chunk @ W2[cbase:cbase+128, :], two 64-hid subtiles ----
#pragma unroll
    for (int sub = 0; sub < 2; ++sub) {
      if (wn == sub) {
        // this wave pair owns hid cols sub*64..+63: write h hi/lo into Ah/Al
#pragma unroll
        for (int m = 0; m < 4; ++m)
#pragma unroll
          for (int q = 0; q < 4; ++q) {
            int colq = q * 16 + fr;
            int oct = colq >> 3;
#pragma unroll
            for (int j = 0; j < 4; ++j) {
              int r = wm * 64 + m * 16 + fq * 4 + j;
              float v = acc[m][q][j];
              unsigned hb = f2bf_bits(v);
              unsigned lb = f2bf_bits(v - bf2f_bits(hb));
              int off = r * 64 + slot_sw(r, oct) * 8 + (colq & 7);
              Ah[off] = (ushort)hb;
              Al[off] = (ushort)lb;
            }
          }
      } else {
        // other wave pair stages W2^T subtile into Bh/Bl
        int t2 = wm * 64 + lane;  // 0..127
        int oc = t2 >> 1;         // out col 0..63
        int k0 = (t2 & 1) * 32;
#pragma unroll
        for (int i = 0; i < 32; ++i) {
          int k = k0 + i;
          float v = w2[(size_t)(cbase + sub * 64 + k) * GOUT_DIM + oc];
          unsigned hb = f2bf_bits(v);
          unsigned lb = f2bf_bits(v - bf2f_bits(hb));
          int off = oc * 64 + slot_sw(oc, k >> 3) * 8 + (k & 7);
          Bh[off] = (ushort)hb;
          Bl[off] = (ushort)lb;
        }
      }
      __syncthreads();
#pragma unroll
      for (int kk = 0; kk < 2; ++kk) {
        int koct = kk * 4 + fq;
        short8 bH[4], bL[4];
#pragma unroll
        for (int q2 = 0; q2 < 4; ++q2) {
          int c2 = q2 * 16 + fr;
          int off = c2 * 64 + slot_sw(c2, koct) * 8;
          bH[q2] = *reinterpret_cast<const short8*>(&Bh[off]);
          bL[q2] = *reinterpret_cast<const short8*>(&Bl[off]);
        }
#pragma unroll
        for (int m2 = 0; m2 < 2; ++m2) {
          int r2 = wave * 32 + m2 * 16 + fr;
          int off = r2 * 64 + slot_sw(r2, koct) * 8;
          short8 aH = *reinterpret_cast<const short8*>(&Ah[off]);
          short8 aL = *reinterpret_cast<const short8*>(&Al[off]);
#pragma unroll
          for (int q2 = 0; q2 < 4; ++q2) {
            f32x4 t = acc2[m2][q2];
            t = __builtin_amdgcn_mfma_f32_16x16x32_bf16(aH, bL[q2], t, 0, 0, 0);
            t = __builtin_amdgcn_mfma_f32_16x16x32_bf16(aL, bH[q2], t, 0, 0, 0);
            t = __builtin_amdgcn_mfma_f32_16x16x32_bf16(aH, bH[q2], t, 0, 0, 0);
            acc2[m2][q2] = t;
          }
        }
      }
      __syncthreads();
    }
  }

  // epilogue: write plane [n][64]
#pragma unroll
  for (int m2 = 0; m2 < 2; ++m2)
#pragma unroll
    for (int q2 = 0; q2 < 4; ++q2) {
      int col = q2 * 16 + fr;
#pragma unroll
      for (int j = 0; j < 4; ++j) {
        int grow = rowbase + wave * 32 + m2 * 16 + fq * 4 + j;
        if (grow < n) plane[(size_t)grow * GOUT_DIM + col] = acc2[m2][q2][j];
      }
    }
}

// ---------------- combine init: out = sigmoid(h0 . s) * h0 ----------------

__global__ void k_combine(const float* __restrict__ h0, const float* __restrict__ s,
                          float* __restrict__ out, int n) {
  int wave = (int)((blockIdx.x * blockDim.x + threadIdx.x) >> 6);
  int lane = threadIdx.x & 63;
  if (wave >= n) return;
  float v = h0[(size_t)wave * GOUT_DIM + lane];
  float dot = v * s[lane];
#pragma unroll
  for (int off = 32; off; off >>= 1) dot += __shfl_xor(dot, off);
  float sig = 1.f / (1.f + __expf(-dot));
  out[(size_t)wave * GOUT_DIM + lane] = sig * v;
}

// ---------------- SPMM hop: 8-deep gather pipeline ----------------

__global__ __launch_bounds__(256) void k_spmm(const int* __restrict__ rp,
                                              const int2* __restrict__ epk,
                                              const float* __restrict__ hin,
                                              float* __restrict__ hout,
                                              const float* __restrict__ s,
                                              float* __restrict__ out, int n) {
  int wave = (int)((blockIdx.x * blockDim.x + threadIdx.x) >> 6);
  int lane = threadIdx.x & 63;
  if (wave >= n) return;
  int e0 = __builtin_amdgcn_readfirstlane(rp[wave]);
  int e1 = __builtin_amdgcn_readfirstlane(rp[wave + 1]);
  float sl = s[lane];
  float a0 = 0.f, a1 = 0.f, a2 = 0.f, a3 = 0.f;
  int em = e0 + ((e1 - e0) & ~7);
  for (int e = e0; e < em; e += 8) {
    int2 p0 = epk[e + 0], p1 = epk[e + 1], p2 = epk[e + 2], p3 = epk[e + 3];
    int2 p4 = epk[e + 4], p5 = epk[e + 5], p6 = epk[e + 6], p7 = epk[e + 7];
    float v0 = hin[(size_t)p0.x * GOUT_DIM + lane];
    float v1 = hin[(size_t)p1.x * GOUT_DIM + lane];
    float v2 = hin[(size_t)p2.x * GOUT_DIM + lane];
    float v3 = hin[(size_t)p3.x * GOUT_DIM + lane];
    float v4 = hin[(size_t)p4.x * GOUT_DIM + lane];
    float v5 = hin[(size_t)p5.x * GOUT_DIM + lane];
    float v6 = hin[(size_t)p6.x * GOUT_DIM + lane];
    float v7 = hin[(size_t)p7.x * GOUT_DIM + lane];
    a0 = fmaf(__int_as_float(p0.y), v0, a0);
    a1 = fmaf(__int_as_float(p1.y), v1, a1);
    a2 = fmaf(__int_as_float(p2.y), v2, a2);
    a3 = fmaf(__int_as_float(p3.y), v3, a3);
    a0 = fmaf(__int_as_float(p4.y), v4, a0);
    a1 = fmaf(__int_as_float(p5.y), v5, a1);
    a2 = fmaf(__int_as_float(p6.y), v6, a2);
    a3 = fmaf(__int_as_float(p7.y), v7, a3);
  }
  if (em < e1) {
    int last = e1 - 1;
#pragma unroll
    for (int j = 0; j < 8; ++j) {
      int e = em + j;
      int ec = e < last ? e : last;
      int2 p = epk[ec];
      float w = (e < e1) ? __int_as_float(p.y) : 0.f;
      float v = hin[(size_t)p.x * GOUT_DIM + lane];
      if (j & 1)
        a1 = fmaf(w, v, a1);
      else
        a0 = fmaf(w, v, a0);
    }
  }
  float acc = (a0 + a1) + (a2 + a3);
  hout[(size_t)wave * GOUT_DIM + lane] = acc;
  float dot = acc * sl;
#pragma unroll
  for (int off = 32; off; off >>= 1) dot += __shfl_xor(dot, off);
  float sig = 1.f / (1.f + __expf(-dot));
  out[(size_t)wave * GOUT_DIM + lane] += sig * acc;
}

// ---------------- launch ----------------

static inline char* align256(char* p) {
  return (char*)(((uintptr_t)p + 255) & ~(uintptr_t)255);
}

extern "C" void kernel_launch(void* const* d_in, const int* in_sizes, int n_in,
                              void* d_out, int out_size, void* d_ws, size_t ws_size,
                              hipStream_t stream) {
  const float* x = (const float*)d_in[0];
  const int* row = (const int*)d_in[1];
  const int* col = (const int*)d_in[2];
  const float* ew = (const float*)d_in[3];
  const float* W1 = (const float*)d_in[4];
  const float* b1 = (const float*)d_in[5];
  const float* W2 = (const float*)d_in[6];
  const float* b2 = (const float*)d_in[7];
  const float* s = (const float*)d_in[8];
  float* out = (float*)d_out;

  int N = in_sizes[0] / GIN_DIM;
  int E = in_sizes[1];

  char* w = (char*)d_ws;
  float* planeA = (float*)w;  w = align256(w + (size_t)N * GOUT_DIM * sizeof(float));
  float* planeB = (float*)w;  w = align256(w + (size_t)N * GOUT_DIM * sizeof(float));
  int* cnt = (int*)w;         w = align256(w + (size_t)N * sizeof(int));
  int* rp = (int*)w;          w = align256(w + ((size_t)N + 1) * sizeof(int));
  int* nxt = (int*)w;         w = align256(w + (size_t)N * sizeof(int));
  int* bsum = (int*)w;        w = align256(w + 256 * sizeof(int));
  int2* epk = (int2*)w;       w = align256(w + (size_t)E * sizeof(int2));
  ushort* w1h = (ushort*)w;   w = align256(w + (size_t)GIN_DIM * GHID_DIM * sizeof(ushort));
  ushort* w1l = (ushort*)w;   w = align256(w + (size_t)GIN_DIM * GHID_DIM * sizeof(ushort));

  int nb = (N + 1023) / 1024;
  int nbe = (E + 1023) / 1024;
  float sliceScale = (float)NSLICE / (float)N;

  // CSR build (sliced count + scatter)
  hipMemsetAsync(cnt, 0, (size_t)N * sizeof(int), stream);
  k_count<<<nbe * NSLICE, 256, 0, stream>>>(row, cnt, E, sliceScale);
  k_scan1<<<nb, 256, 0, stream>>>(cnt, bsum, N);
  k_scan2<<<1, 128, 0, stream>>>(bsum, rp, nb, N);
  k_scan3<<<nb, 256, 0, stream>>>(cnt, bsum, rp, nxt, N);
  k_scatter<<<nbe * NSLICE, 256, 0, stream>>>(row, col, ew, nxt, epk, E, sliceScale);

  // W1 transpose + bf16 split
  k_w1t<<<dim3(16, 16), 1024, 0, stream>>>(W1, w1h, w1l);

  // fused dense front
  k_dense<<<(N + 127) / 128, 256, 0, stream>>>(x, w1h, w1l, b1, W2, b2, planeA, N);

  // out = sigmoid(h0.s)*h0
  k_combine<<<(N + 3) / 4, 256, 0, stream>>>(planeA, s, out, N);

  // 10 hops, online accumulation into out
  const float* hin = planeA;
  float* hout = planeB;
  for (int k = 0; k < GHOP; ++k) {
    k_spmm<<<(N + 3) / 4, 256, 0, stream>>>(rp, epk, hin, hout, s, out, N);
    float* t = (float*)hin;
    hin = hout;
    hout = t;
  }
}